// Round 1
// baseline (7605.534 us; speedup 1.0000x reference)
//
#include <hip/hip_runtime.h>
#include <hip/hip_bf16.h>

// Leaky RNN h_{t+1} = 0.9 h_t + 0.1 (h_t A^T + x_t), NS=32, T=2048, N=1024.
// Strategy: chunked warm-up. 256 independent workgroups, chunk c owns outputs
// t in [8c, 8c+8). Each starts W=128 steps early from h=0 (error decays as
// ||B||^W <= 0.94^128 ~ 3.6e-4), or exactly from h0 when the window hits t=0.
// Per step: [32,1024]x[1024,1024] bf16 MFMA GEMM, A streamed from L2 (resident,
// 2MB/XCD), h state fp32 in registers (MFMA C-layout), bf16 copy in LDS.

#define NSAMP 32
#define TSTEPS 2048
#define NDIM 1024
#define CHUNK_L 8
#define WARM 128
#define NCHUNK (TSTEPS / CHUNK_L)   // 256
#define HS_STRIDE 1544              // bf16 elems/row; >80KB LDS => 1 block/CU; stride%32(dw)=4 -> conflict-free b128

typedef __attribute__((ext_vector_type(8))) short short8;
typedef __attribute__((ext_vector_type(4))) float floatx4;

// Bp[kt][n][kk] = bf16(A[n][kt*32+kk]) : B-operand (A^T) packed so each lane's
// 8-elem fragment (n = lane&15, k = kt*32 + quad*8 + j) is 16B contiguous and
// the wave's 64 lanes cover 1KB densely.
__global__ __launch_bounds__(256)
void prep_A_kernel(const float* __restrict__ A, __hip_bfloat16* __restrict__ Bp) {
    int idx = blockIdx.x * 256 + threadIdx.x;   // idx = n*1024 + k
    int k  = idx & (NDIM - 1);
    int n  = idx >> 10;
    int kt = k >> 5, kk = k & 31;
    Bp[((kt << 10) + n) * 32 + kk] = __float2bfloat16(A[idx]);
}

__global__ __launch_bounds__(512, 2)
void rnn_chunk_kernel(const float* __restrict__ inp,
                      const float* __restrict__ h0,
                      const __hip_bfloat16* __restrict__ Bp,
                      float* __restrict__ out) {
    __shared__ __hip_bfloat16 Hs[NSAMP * HS_STRIDE];

    const int c    = blockIdx.x;     // chunk id
    const int tid  = threadIdx.x;
    const int lane = tid & 63;
    const int wave = tid >> 6;       // 0..7, owns n-tiles wave*8 .. wave*8+7
    const int q    = lane >> 4;      // quad
    const int m16  = lane & 15;

    const int out_lo  = c * CHUNK_L;
    const int out_hi  = out_lo + CHUNK_L;
    const int t_start = (out_lo > WARM) ? (out_lo - WARM) : 0;

    // fragment element (mt, j, r): s = mt*16 + q*4 + r ; n = (wave*8+j)*16 + m16
    float hreg[2][8][4];   // fp32 master state, persistent across steps

    #pragma unroll
    for (int mt = 0; mt < 2; ++mt)
    #pragma unroll
    for (int j = 0; j < 8; ++j) {
        const int n = (wave * 8 + j) * 16 + m16;
        #pragma unroll
        for (int r = 0; r < 4; ++r) {
            const int s = mt * 16 + q * 4 + r;
            const float h = (t_start == 0) ? h0[s * NDIM + n] : 0.0f;
            hreg[mt][j][r] = h;
            Hs[s * HS_STRIDE + n] = __float2bfloat16(h);
            if (c == 0) out[((size_t)s * TSTEPS) * NDIM + n] = h;   // t=0 output
        }
    }
    __syncthreads();

    for (int t = t_start + 1; t < out_hi; ++t) {
        floatx4 acc[2][8] = {};

        // acc = H_bf16 @ A^T_bf16 ; H from LDS (A-frag), A^T streamed from L2 (B-frag)
        for (int kt = 0; kt < 32; ++kt) {
            const short8 a0 = *(const short8*)&Hs[(m16     ) * HS_STRIDE + kt * 32 + q * 8];
            const short8 a1 = *(const short8*)&Hs[(m16 + 16) * HS_STRIDE + kt * 32 + q * 8];
            #pragma unroll
            for (int j = 0; j < 8; ++j) {
                const short8 b = *(const short8*)&Bp[(size_t)(kt * NDIM + (wave * 8 + j) * 16 + m16) * 32 + q * 8];
                acc[0][j] = __builtin_amdgcn_mfma_f32_16x16x32_bf16(a0, b, acc[0][j], 0, 0, 0);
                acc[1][j] = __builtin_amdgcn_mfma_f32_16x16x32_bf16(a1, b, acc[1][j], 0, 0, 0);
            }
        }

        __syncthreads();   // everyone done reading Hs(h_{t-1})

        const bool emit = (t >= out_lo);
        #pragma unroll
        for (int mt = 0; mt < 2; ++mt)
        #pragma unroll
        for (int j = 0; j < 8; ++j) {
            const int n = (wave * 8 + j) * 16 + m16;
            #pragma unroll
            for (int r = 0; r < 4; ++r) {
                const int s = mt * 16 + q * 4 + r;
                const float x = inp[((size_t)s * TSTEPS + (t - 1)) * NDIM + n];
                const float h = 0.9f * hreg[mt][j][r] + 0.1f * (acc[mt][j][r] + x);
                hreg[mt][j][r] = h;
                Hs[s * HS_STRIDE + n] = __float2bfloat16(h);
                if (emit) out[((size_t)s * TSTEPS + t) * NDIM + n] = h;
            }
        }
        __syncthreads();   // Hs(h_t) visible before next GEMM
    }
}

extern "C" void kernel_launch(void* const* d_in, const int* in_sizes, int n_in,
                              void* d_out, int out_size, void* d_ws, size_t ws_size,
                              hipStream_t stream) {
    const float* inp = (const float*)d_in[0];   // [32, 2048, 1024]
    const float* A   = (const float*)d_in[1];   // [1024, 1024]
    const float* h0  = (const float*)d_in[2];   // [32, 1024]
    float* out = (float*)d_out;                 // [32, 2048, 1024]
    __hip_bfloat16* Bp = (__hip_bfloat16*)d_ws; // 2 MB packed bf16 A^T

    hipLaunchKernelGGL(prep_A_kernel, dim3((NDIM * NDIM) / 256), dim3(256), 0, stream, A, Bp);
    hipLaunchKernelGGL(rnn_chunk_kernel, dim3(NCHUNK), dim3(512), 0, stream, inp, h0, Bp, out);
}